// Round 3
// baseline (157.987 us; speedup 1.0000x reference)
//
#include <hip/hip_runtime.h>
#include <stdint.h>

#define NN 16384
#define MM 16384
#define DD 8
#define DV 16
#define WAVES 4
#define MT 2                        // 16-row m-tiles per wave
#define ROWS_WAVE (MT * 16)         // 32
#define ROWS_BLK (WAVES * ROWS_WAVE)// 128
#define JSPLIT 16
#define JCHUNK (MM / JSPLIT)        // 1024
#define J32 (JCHUNK / 32)           // 32 iterations per block

typedef short bf8 __attribute__((ext_vector_type(8)));   // 8 bf16 (4 VGPR)
typedef short s2v __attribute__((ext_vector_type(2)));   // 2 bf16, one b32 store
typedef float f32x4 __attribute__((ext_vector_type(4))); // MFMA C/D

#define C3SQ 10.406844905028037f     /* 5*log2(e)^2 : folded into tables */
#define C2S  (1.2909944487358056f / 10.406844905028037f)  /* c2/c3sq */
#define LN2  0.6931471805599453f

// PWL table for k(z) = (1 + LN2*t + C2S*z) * 2^-t, t = sqrt(z).
// Log-spaced segments via float bits: exponent range 2^-8 .. 2^10,
// 32 segments/octave (top-5 mantissa bits). 18 octaves * 32 = 576 entries.
// R15: SPLIT B/S tables (two ds_read_b32, 1 bank/lane, ~2-way ~ free) and
// signed-int bit clamp (med3_i32: negative-noise z -> segment 0 -> k~1).
#define KTAB_N 576
#define KTAB_SHIFT 18
#define KTAB_OFS 3808   /* (127-8) << 5 */
#define KTAB_LO 0x3B800000  /* KTAB_OFS << 18  == bits(2^-8)  */
#define KTAB_HI 0x447C0000  /* (KTAB_OFS+575) << 18 (last segment, zeros) */

__device__ __forceinline__ unsigned short f2bf(float f) {
    union { float f; uint32_t u; } c; c.f = f;
    uint32_t u = c.u + 0x7FFF + ((c.u >> 16) & 1);       // RNE
    return (unsigned short)(u >> 16);
}
__device__ __forceinline__ float bf2f(unsigned short h) {
    union { float f; uint32_t u; } c; c.u = ((uint32_t)h) << 16;
    return c.f;
}

#define BF16_ONE ((short)0x3F80)

// Tables with the SCALED d2 fold: MFMA emits z = c3sq*d2 directly.
//   quads 0..2 of B hold w = -2*c3sq*y (split hi,hi,lo AFTER fp32 scaling)
//   quad 3: A {1,1,csx_hi,csx_lo} x B {csy_hi,csy_lo,1,1}, c* = c3sq-scaled
// btbl K-order PERMUTED to match interleaved klds columns:
//   k -> j_local = (k>>1) + ((k&1)<<4)
__global__ __launch_bounds__(256) void prep_frags(const float* __restrict__ ls,
                                                  const float* __restrict__ y,
                                                  const float* __restrict__ b,
                                                  bf8* __restrict__ ytbl,
                                                  bf8* __restrict__ btbl,
                                                  float4* __restrict__ outz) {
    const int tile = blockIdx.x * 4 + (threadIdx.x >> 6);  // 0..1023 (j16 tiles)
    const int lane = threadIdx.x & 63;
    const int n = lane & 15, quad = lane >> 4;

    // zero d_out: 256 blocks * 256 threads * 16B = 1 MB
    outz[blockIdx.x * 256 + threadIdx.x] = make_float4(0.f, 0.f, 0.f, 0.f);

    float lsv[DD];
#pragma unroll
    for (int d = 0; d < DD; ++d) lsv[d] = ls[d];

    const float4* yr4 = (const float4*)(y + (size_t)(tile * 16 + n) * DD);
    float4 ya = yr4[0], yb = yr4[1];
    float yv[DD] = {ya.x, ya.y, ya.z, ya.w, yb.x, yb.y, yb.z, yb.w};

    float syv = 0.f;
    unsigned short wh[DD], wl[DD];
#pragma unroll
    for (int d = 0; d < DD; ++d) {
        syv = fmaf(lsv[d] * yv[d], yv[d], syv);
        float w = -2.f * C3SQ * yv[d];          // scale in fp32, THEN split
        wh[d] = f2bf(w);
        wl[d] = f2bf(w - bf2f(wh[d]));
    }

    bf8 fr;
    if (quad < 3) {
#pragma unroll
        for (int d = 0; d < DD; ++d)
            fr[d] = (short)((quad == 2) ? wl[d] : wh[d]);
    } else {
        float csy = C3SQ * syv;
        unsigned short sh = f2bf(csy);
        unsigned short sl = f2bf(csy - bf2f(sh));
        fr[0] = (short)sh;      // k=24: 1 * csy_hi
        fr[1] = (short)sl;      // k=25: 1 * csy_lo
        fr[2] = BF16_ONE;       // k=26: csx_hi * 1
        fr[3] = BF16_ONE;       // k=27: csx_lo * 1
        fr[4] = 0; fr[5] = 0; fr[6] = 0; fr[7] = 0;
    }
    ytbl[tile * 64 + lane] = fr;

    if (tile < MM / 32) {             // j32 tiles for phase B, PERMUTED K-order
        bf8 bfr;
#pragma unroll
        for (int s = 0; s < 8; ++s) {
            int k = quad * 8 + s;
            int jl = (k >> 1) + ((k & 1) << 4);   // interleaved klds col -> j
            float bv = b[(size_t)(tile * 32 + jl) * DV + n];
            bfr[s] = (short)f2bf(bv);
        }
        btbl[tile * 64 + lane] = bfr;
    }
}

// R15 = R12 structure with the transform as a conflict-FREE PWL gather:
//  - R14 post-mortem: b64 float2 gather = 2 banks/lane -> ~4-way conflicts
//    (15.7M cy) + unfoldable index VALU ate the entire trans saving.
//  - Split B/S f32 tables: 2x ds_read_b32 (1 bank/lane, random ~2-way = free,
//    m136), second read folds to offset:2304 off the SAME address register.
//  - Signed-bit clamp (med3_i32 pattern) on RAW z bits: rounding-noise
//    negatives clamp to segment 0 (k~1, correct limit); kills fmax + 2 clamps.
//  - Per element: clamp,sub,shr,addr + 2 DS + fma  (~10 VALU cy vs R12's ~24
//    with quarter-rate sqrt+exp2).
//  - JSPLIT 32->16: 2048 blocks = exactly 8/CU, halves atomic epilogue.
__global__ __launch_bounds__(256, 8) void matern_mfma(const float* __restrict__ ls,
                                                      const float* __restrict__ x,
                                                      const bf8* __restrict__ ytbl,
                                                      const bf8* __restrict__ btbl,
                                                      float* __restrict__ out) {
    const int t = threadIdx.x;
    const int lane = t & 63, wave = t >> 6;
    const int n = lane & 15, quad = lane >> 4;
    const int waverow = blockIdx.x * ROWS_BLK + wave * ROWS_WAVE;

    // [wave][mt][m][40]: 80B rows; b32 writes (20*row+n)%32 -> 2-way free;
    // b128 reads 16B-aligned, 2-way free (R5-proven).
    __shared__ __attribute__((aligned(16))) unsigned short klds[WAVES][MT][16][40];
    // [0][i] = intercept B, [1][i] = slope S; contiguous so S-read is
    // ds_read_b32 offset:2304 off the B address register.
    __shared__ __attribute__((aligned(16))) float ktab2[2][KTAB_N];

    // Build the PWL table (once per block, ~3 entries/thread, trivial cost).
    for (int i = t; i < KTAB_N; i += 256) {
        uint32_t b0 = ((uint32_t)(i + KTAB_OFS)) << KTAB_SHIFT;   // left edge bits
        float z0 = __uint_as_float(b0);
        float z1 = __uint_as_float(b0 + (1u << KTAB_SHIFT));      // right edge
        float t0 = __builtin_amdgcn_sqrtf(z0);
        float t1 = __builtin_amdgcn_sqrtf(z1);
        float k0 = fmaf(C2S, z0, fmaf(LN2, t0, 1.f)) * __builtin_amdgcn_exp2f(-t0);
        float k1 = fmaf(C2S, z1, fmaf(LN2, t1, 1.f)) * __builtin_amdgcn_exp2f(-t1);
        float S = (k1 - k0) / (z1 - z0);
        float B = fmaf(-S, z0, k0);
        if (i == KTAB_N - 1) { S = 0.f; B = 0.f; }   // z >= ~984: k < 1e-9 -> 0
        ktab2[0][i] = B;
        ktab2[1][i] = S;
    }
    __syncthreads();   // table read-only hereafter; klds stays per-wave

    float lsv[DD];
#pragma unroll
    for (int d = 0; d < DD; ++d) lsv[d] = ls[d];

    // A-frags: quad 0/2 -> xls_hi, quad 1 -> xls_lo, quad 3 -> {1,1,csx_hi,csx_lo}
    bf8 afrag[MT];
#pragma unroll
    for (int mt = 0; mt < MT; ++mt) {
        const float* xr = x + (size_t)(waverow + mt * 16 + n) * DD;
        float sx = 0.f;
        unsigned short xh[DD], xl[DD];
#pragma unroll
        for (int d = 0; d < DD; ++d) {
            float xv = xr[d];
            float xlsv = lsv[d] * xv;
            sx = fmaf(xlsv, xv, sx);
            xh[d] = f2bf(xlsv);
            xl[d] = f2bf(xlsv - bf2f(xh[d]));
        }
        bf8 fr;
        if (quad == 3) {
            float csx = C3SQ * sx;               // scale in fp32, THEN split
            unsigned short sh = f2bf(csx);
            unsigned short sl = f2bf(csx - bf2f(sh));
            fr[0] = BF16_ONE;   // k=24: 1 * csy_hi
            fr[1] = BF16_ONE;   // k=25: 1 * csy_lo
            fr[2] = (short)sh;  // k=26: csx_hi * 1
            fr[3] = (short)sl;  // k=27: csx_lo * 1
            fr[4] = 0; fr[5] = 0; fr[6] = 0; fr[7] = 0;
        } else {
#pragma unroll
            for (int d = 0; d < DD; ++d)
                fr[d] = (short)((quad == 1) ? xl[d] : xh[d]);
        }
        afrag[mt] = fr;
    }

    f32x4 acc[MT];
#pragma unroll
    for (int mt = 0; mt < MT; ++mt) acc[mt] = (f32x4){0.f, 0.f, 0.f, 0.f};

    const int tile16base = blockIdx.y * (JCHUNK / 16);
    const int tile32base = blockIdx.y * (JCHUNK / 32);

#pragma unroll 1
    for (int it = 0; it < J32; ++it) {
        const int tl0 = tile16base + it * 2;
        bf8 yA = ytbl[(size_t)tl0 * 64 + lane];
        bf8 yB = ytbl[(size_t)(tl0 + 1) * 64 + lane];
        bf8 bb = btbl[(size_t)(tile32base + it) * 64 + lane];

#pragma unroll
        for (int mt = 0; mt < MT; ++mt) {
            f32x4 z4 = (f32x4){0.f, 0.f, 0.f, 0.f};
            f32x4 s0 = __builtin_amdgcn_mfma_f32_16x16x32_bf16(afrag[mt], yA, z4, 0, 0, 0);
            f32x4 s1 = __builtin_amdgcn_mfma_f32_16x16x32_bf16(afrag[mt], yB, z4, 0, 0, 0);
#pragma unroll
            for (int s = 0; s < 4; ++s) {
                // s0/s1 ARE c3sq*d2. Clamp RAW BITS as signed int:
                // negative-noise z -> sign bit set -> clamps to LO -> seg 0
                // (k ~ 1 + S0*z_noise, correct limit). z > table -> last seg,
                // S=B=0 -> k=0 regardless of z fed to the fma.
                float z0 = s0[s];
                float z1 = s1[s];
                int c0 = __float_as_int(z0);
                int c1 = __float_as_int(z1);
                c0 = c0 < KTAB_LO ? KTAB_LO : (c0 > KTAB_HI ? KTAB_HI : c0);
                c1 = c1 < KTAB_LO ? KTAB_LO : (c1 > KTAB_HI ? KTAB_HI : c1);
                int i0 = (c0 - KTAB_LO) >> KTAB_SHIFT;
                int i1 = (c1 - KTAB_LO) >> KTAB_SHIFT;
                float B0 = ktab2[0][i0];          // ds_read_b32 (1 bank/lane)
                float S0 = ktab2[1][i0];          // same addr, offset:2304
                float B1 = ktab2[0][i1];
                float S1 = ktab2[1][i1];
                float k0 = fmaf(S0, z0, B0);
                float k1 = fmaf(S1, z1, B1);
                s2v w;
#if __has_builtin(__builtin_amdgcn_cvt_pk_bf16_f32)
                typedef __bf16 bf2v __attribute__((ext_vector_type(2)));
                bf2v pk = __builtin_amdgcn_cvt_pk_bf16_f32(k0, k1);
                union { bf2v v; s2v s; } cv; cv.v = pk;
                w = cv.s;
#else
                // round-half-up bf16 (k>=0): proven 2-op path per value
                w[0] = (short)((__float_as_uint(k0) + 0x8000u) >> 16);
                w[1] = (short)((__float_as_uint(k1) + 0x8000u) >> 16);
#endif
                // one b32 store: cols 2n (tile0) / 2n+1 (tile1), interleaved
                *(s2v*)&klds[wave][mt][quad * 4 + s][2 * n] = w;
            }
        }
        // C/D->A: lane reads A'[m=lane&15][k=quad*8+s] as one 16B LDS read;
        // interleaved cols match btbl's permuted K-order.
#pragma unroll
        for (int mt = 0; mt < MT; ++mt) {
            const bf8* kp = (const bf8*)&klds[wave][mt][n][quad * 8];
            acc[mt] = __builtin_amdgcn_mfma_f32_16x16x32_bf16(*kp, bb, acc[mt], 0, 0, 0);
        }
    }

    // Epilogue: D layout row=quad*4+s, col=n; JSPLIT partial sums via atomics
#pragma unroll
    for (int mt = 0; mt < MT; ++mt)
#pragma unroll
        for (int s = 0; s < 4; ++s) {
            const int row = waverow + mt * 16 + quad * 4 + s;
            atomicAdd(out + (size_t)row * DV + n, acc[mt][s]);
        }
}

extern "C" void kernel_launch(void* const* d_in, const int* in_sizes, int n_in,
                              void* d_out, int out_size, void* d_ws, size_t ws_size,
                              hipStream_t stream) {
    const float* ls = (const float*)d_in[0];
    const float* x  = (const float*)d_in[1];
    const float* y  = (const float*)d_in[2];
    const float* b  = (const float*)d_in[3];
    float* out = (float*)d_out;

    char* ws = (char*)d_ws;
    bf8* ytbl = (bf8*)ws;                        // 1024*64*16B = 1 MB
    bf8* btbl = (bf8*)(ws + (1 << 20));          // 512*64*16B  = 512 KB

    prep_frags<<<MM / 64, 256, 0, stream>>>(ls, y, b, ytbl, btbl, (float4*)out);
    matern_mfma<<<dim3(NN / ROWS_BLK, JSPLIT), 256, 0, stream>>>(ls, x, ytbl, btbl, out);
}

// Round 5
// 135.348 us; speedup vs baseline: 1.1673x; 1.1673x over previous
//
#include <hip/hip_runtime.h>
#include <stdint.h>

#define NN 16384
#define MM 16384
#define DD 8
#define DV 16
#define WAVES 4
#define MT 2                        // 16-row m-tiles per wave
#define ROWS_WAVE (MT * 16)         // 32
#define ROWS_BLK (WAVES * ROWS_WAVE)// 128
#define JSPLIT 16
#define JCHUNK (MM / JSPLIT)        // 1024
#define J32 (JCHUNK / 32)           // 32 iterations per block

typedef short bf8 __attribute__((ext_vector_type(8)));   // 8 bf16 (4 VGPR)
typedef float f32x4 __attribute__((ext_vector_type(4))); // MFMA C/D

#define C3SQ 10.406844905028037f     /* 5*log2(e)^2 : folded into tables */
#define C2S  (1.2909944487358056f / 10.406844905028037f)  /* c2/c3sq */
#define LN2  0.6931471805599453f

__device__ __forceinline__ unsigned short f2bf(float f) {
    union { float f; uint32_t u; } c; c.f = f;
    uint32_t u = c.u + 0x7FFF + ((c.u >> 16) & 1);       // RNE
    return (unsigned short)(u >> 16);
}
__device__ __forceinline__ float bf2f(unsigned short h) {
    union { float f; uint32_t u; } c; c.u = ((uint32_t)h) << 16;
    return c.f;
}

#define BF16_ONE ((short)0x3F80)

// Matern transform: z = c3sq*d2 (from MFMA), k = (1 + LN2*t + C2S*z)*2^-t,
// t = sqrt(|z|). fabs folds into sqrt's VOP3 |src|; -t folds into exp2's neg.
__device__ __forceinline__ float ktrans(float z) {
    float a = __builtin_fabsf(z);
    float t = __builtin_amdgcn_sqrtf(a);
    float e = __builtin_amdgcn_exp2f(-t);
    return fmaf(C2S, a, fmaf(LN2, t, 1.f)) * e;
}

// Pack two f32 -> one dword of 2 bf16 (lo=k0, hi=k1).
__device__ __forceinline__ unsigned int pk2(float k0, float k1) {
#if __has_builtin(__builtin_amdgcn_cvt_pk_bf16_f32)
    typedef __bf16 bf2v __attribute__((ext_vector_type(2)));
    union { bf2v v; unsigned int u; } cv;
    cv.v = __builtin_amdgcn_cvt_pk_bf16_f32(k0, k1);
    return cv.u;
#else
    unsigned int u0 = __float_as_uint(k0) + 0x8000u;   // round-half-up, k>=0
    unsigned int u1 = __float_as_uint(k1) + 0x8000u;
    return __builtin_amdgcn_perm(u1, u0, 0x07060302u); // {hi16(u1),hi16(u0)}
#endif
}

// Tables with the SCALED d2 fold: MFMA emits z = c3sq*d2 directly.
//   quads 0..2 of B hold w = -2*c3sq*y (split hi,hi,lo AFTER fp32 scaling)
//   quad 3: A {1,1,csx_hi,csx_lo} x B {csy_hi,csy_lo,1,1}, c* = c3sq-scaled
// R16 btbl K-order: slot k=8q+i -> j = 4q + (i&3) + (i>=4 ? 16 : 0), matching
// the REGISTER layout of the swapped first MFMA's C/D (lane holds m=n,
// j = quad*4+s per tile) so the transformed values ARE the A-fragment.
__global__ __launch_bounds__(256) void prep_frags(const float* __restrict__ ls,
                                                  const float* __restrict__ y,
                                                  const float* __restrict__ b,
                                                  bf8* __restrict__ ytbl,
                                                  bf8* __restrict__ btbl,
                                                  float4* __restrict__ outz) {
    const int tile = blockIdx.x * 4 + (threadIdx.x >> 6);  // 0..1023 (j16 tiles)
    const int lane = threadIdx.x & 63;
    const int n = lane & 15, quad = lane >> 4;

    // zero d_out: 256 blocks * 256 threads * 16B = 1 MB
    outz[blockIdx.x * 256 + threadIdx.x] = make_float4(0.f, 0.f, 0.f, 0.f);

    float lsv[DD];
#pragma unroll
    for (int d = 0; d < DD; ++d) lsv[d] = ls[d];

    const float4* yr4 = (const float4*)(y + (size_t)(tile * 16 + n) * DD);
    float4 ya = yr4[0], yb = yr4[1];
    float yv[DD] = {ya.x, ya.y, ya.z, ya.w, yb.x, yb.y, yb.z, yb.w};

    float syv = 0.f;
    unsigned short wh[DD], wl[DD];
#pragma unroll
    for (int d = 0; d < DD; ++d) {
        syv = fmaf(lsv[d] * yv[d], yv[d], syv);
        float w = -2.f * C3SQ * yv[d];          // scale in fp32, THEN split
        wh[d] = f2bf(w);
        wl[d] = f2bf(w - bf2f(wh[d]));
    }

    bf8 fr;
    if (quad < 3) {
#pragma unroll
        for (int d = 0; d < DD; ++d)
            fr[d] = (short)((quad == 2) ? wl[d] : wh[d]);
    } else {
        float csy = C3SQ * syv;
        unsigned short sh = f2bf(csy);
        unsigned short sl = f2bf(csy - bf2f(sh));
        fr[0] = (short)sh;      // k=24: 1 * csy_hi
        fr[1] = (short)sl;      // k=25: 1 * csy_lo
        fr[2] = BF16_ONE;       // k=26: csx_hi * 1
        fr[3] = BF16_ONE;       // k=27: csx_lo * 1
        fr[4] = 0; fr[5] = 0; fr[6] = 0; fr[7] = 0;
    }
    ytbl[tile * 64 + lane] = fr;

    if (tile < MM / 32) {             // j32 tiles for phase B, register K-order
        bf8 bfr;
#pragma unroll
        for (int s = 0; s < 8; ++s) {
            int k = quad * 8 + s;
            int q = k >> 3, r = k & 7;
            int jl = q * 4 + (r & 3) + ((r & 4) ? 16 : 0);
            float bv = b[(size_t)(tile * 32 + jl) * DV + n];
            bfr[s] = (short)f2bf(bv);
        }
        btbl[tile * 64 + lane] = bfr;
    }
}

// R16 = R12 transform (trans unit; table attempts R14/R15 refuted: random
// gathers are ~5-way bank-conflicted regardless of access width) with the
// klds LDS round-trip DELETED via operand swap:
//   first MFMA computes z^T = mfma(yTile asA, afrag asB) -> lane (n,quad)
//   holds z[j=quad*4+s][m=n]; with btbl's K-order chosen to match, the
//   transformed k-values pack (cvt_pk) STRAIGHT into the second MFMA's
//   A-fragment. The k-slot scheme is A<->B symmetric, so products are
//   bit-identical; acc D layout (row=m, col=v) and epilogue unchanged.
// Removes per iter: 8 ds_write_b32 + 2 ds_read_b128 + lgkm stall + LDS addr
// VALU; kernel now uses ZERO LDS and no barriers.
// JSPLIT=16: 2048 blocks = exactly 8/CU, atomic epilogue traffic halved.
__global__ __launch_bounds__(256, 8) void matern_mfma(const float* __restrict__ ls,
                                                      const float* __restrict__ x,
                                                      const bf8* __restrict__ ytbl,
                                                      const bf8* __restrict__ btbl,
                                                      float* __restrict__ out) {
    const int t = threadIdx.x;
    const int lane = t & 63, wave = t >> 6;
    const int n = lane & 15, quad = lane >> 4;
    const int waverow = blockIdx.x * ROWS_BLK + wave * ROWS_WAVE;

    float lsv[DD];
#pragma unroll
    for (int d = 0; d < DD; ++d) lsv[d] = ls[d];

    // A-frags (used as B operand now; same lane layout: lane&15 = x-row):
    // quad 0/2 -> xls_hi, quad 1 -> xls_lo, quad 3 -> {1,1,csx_hi,csx_lo}
    bf8 afrag[MT];
#pragma unroll
    for (int mt = 0; mt < MT; ++mt) {
        const float* xr = x + (size_t)(waverow + mt * 16 + n) * DD;
        float sx = 0.f;
        unsigned short xh[DD], xl[DD];
#pragma unroll
        for (int d = 0; d < DD; ++d) {
            float xv = xr[d];
            float xlsv = lsv[d] * xv;
            sx = fmaf(xlsv, xv, sx);
            xh[d] = f2bf(xlsv);
            xl[d] = f2bf(xlsv - bf2f(xh[d]));
        }
        bf8 fr;
        if (quad == 3) {
            float csx = C3SQ * sx;               // scale in fp32, THEN split
            unsigned short sh = f2bf(csx);
            unsigned short sl = f2bf(csx - bf2f(sh));
            fr[0] = BF16_ONE;   // k=24: 1 * csy_hi
            fr[1] = BF16_ONE;   // k=25: 1 * csy_lo
            fr[2] = (short)sh;  // k=26: csx_hi * 1
            fr[3] = (short)sl;  // k=27: csx_lo * 1
            fr[4] = 0; fr[5] = 0; fr[6] = 0; fr[7] = 0;
        } else {
#pragma unroll
            for (int d = 0; d < DD; ++d)
                fr[d] = (short)((quad == 1) ? xl[d] : xh[d]);
        }
        afrag[mt] = fr;
    }

    f32x4 acc[MT];
#pragma unroll
    for (int mt = 0; mt < MT; ++mt) acc[mt] = (f32x4){0.f, 0.f, 0.f, 0.f};

    const int tile16base = blockIdx.y * (JCHUNK / 16);
    const int tile32base = blockIdx.y * (JCHUNK / 32);

#pragma unroll 1
    for (int it = 0; it < J32; ++it) {
        const int tl0 = tile16base + it * 2;
        bf8 yA = ytbl[(size_t)tl0 * 64 + lane];
        bf8 yB = ytbl[(size_t)(tl0 + 1) * 64 + lane];
        bf8 bb = btbl[(size_t)(tile32base + it) * 64 + lane];

#pragma unroll
        for (int mt = 0; mt < MT; ++mt) {
            f32x4 z4 = (f32x4){0.f, 0.f, 0.f, 0.f};
            // SWAPPED operands: D = z^T, lane (n,quad) holds
            // z[j = quad*4+s][m = n] for each 16-wide j-tile.
            f32x4 s0 = __builtin_amdgcn_mfma_f32_16x16x32_bf16(yA, afrag[mt], z4, 0, 0, 0);
            f32x4 s1 = __builtin_amdgcn_mfma_f32_16x16x32_bf16(yB, afrag[mt], z4, 0, 0, 0);
            // Transform in registers; pack as the next MFMA's A-fragment:
            // slot k=8*quad+i -> j = 4*quad+(i&3) + (i>=4)*16  (btbl matches)
            union { bf8 v; unsigned int u[4]; } pa;
            pa.u[0] = pk2(ktrans(s0[0]), ktrans(s0[1]));
            pa.u[1] = pk2(ktrans(s0[2]), ktrans(s0[3]));
            pa.u[2] = pk2(ktrans(s1[0]), ktrans(s1[1]));
            pa.u[3] = pk2(ktrans(s1[2]), ktrans(s1[3]));
            acc[mt] = __builtin_amdgcn_mfma_f32_16x16x32_bf16(pa.v, bb, acc[mt], 0, 0, 0);
        }
    }

    // Epilogue: D layout row=quad*4+s (=m), col=n (=v); JSPLIT partials via atomics
#pragma unroll
    for (int mt = 0; mt < MT; ++mt)
#pragma unroll
        for (int s = 0; s < 4; ++s) {
            const int row = waverow + mt * 16 + quad * 4 + s;
            atomicAdd(out + (size_t)row * DV + n, acc[mt][s]);
        }
}

extern "C" void kernel_launch(void* const* d_in, const int* in_sizes, int n_in,
                              void* d_out, int out_size, void* d_ws, size_t ws_size,
                              hipStream_t stream) {
    const float* ls = (const float*)d_in[0];
    const float* x  = (const float*)d_in[1];
    const float* y  = (const float*)d_in[2];
    const float* b  = (const float*)d_in[3];
    float* out = (float*)d_out;

    char* ws = (char*)d_ws;
    bf8* ytbl = (bf8*)ws;                        // 1024*64*16B = 1 MB
    bf8* btbl = (bf8*)(ws + (1 << 20));          // 512*64*16B  = 512 KB

    prep_frags<<<MM / 64, 256, 0, stream>>>(ls, y, b, ytbl, btbl, (float4*)out);
    matern_mfma<<<dim3(NN / ROWS_BLK, JSPLIT), 256, 0, stream>>>(ls, x, ytbl, btbl, out);
}

// Round 6
// 130.093 us; speedup vs baseline: 1.2144x; 1.0404x over previous
//
#include <hip/hip_runtime.h>
#include <stdint.h>

#define NN 16384
#define MM 16384
#define DD 8
#define DV 16
#define WAVES 4
#define MT 2                        // 16-row m-tiles per wave
#define ROWS_WAVE (MT * 16)         // 32
#define ROWS_BLK (WAVES * ROWS_WAVE)// 128
#define JSPLIT 16
#define JCHUNK (MM / JSPLIT)        // 1024
#define J32 (JCHUNK / 32)           // 32 iterations per block

typedef short bf8 __attribute__((ext_vector_type(8)));   // 8 bf16 (4 VGPR)
typedef float f32x4 __attribute__((ext_vector_type(4))); // MFMA C/D

#define C3SQ 10.406844905028037f     /* 5*log2(e)^2 : folded into tables */
#define C2S  (1.2909944487358056f / 10.406844905028037f)  /* c2/c3sq */
#define LN2  0.6931471805599453f

__device__ __forceinline__ unsigned short f2bf(float f) {
    union { float f; uint32_t u; } c; c.f = f;
    uint32_t u = c.u + 0x7FFF + ((c.u >> 16) & 1);       // RNE
    return (unsigned short)(u >> 16);
}
__device__ __forceinline__ float bf2f(unsigned short h) {
    union { float f; uint32_t u; } c; c.u = ((uint32_t)h) << 16;
    return c.f;
}

#define BF16_ONE ((short)0x3F80)

// Matern transform: z = c3sq*d2 (from MFMA), k = (1 + LN2*t + C2S*z)*2^-t,
// t = sqrt(|z|). fabs folds into sqrt's VOP3 |src|; -t folds into exp2's neg.
__device__ __forceinline__ float ktrans(float z) {
    float a = __builtin_fabsf(z);
    float t = __builtin_amdgcn_sqrtf(a);
    float e = __builtin_amdgcn_exp2f(-t);
    return fmaf(C2S, a, fmaf(LN2, t, 1.f)) * e;
}

// Pack two f32 -> one dword of 2 bf16 (lo=k0, hi=k1).
// R17: plain __bf16 casts — clang on gfx950 fuses the pair into ONE
// v_cvt_pk_bf16_f32 (m240: no builtin exists; hand asm and bit-tricks are
// slower). The old __has_builtin guard silently compiled the 3-instr
// fallback (2 add + 1 perm) every round.
__device__ __forceinline__ unsigned int pk2(float k0, float k1) {
    typedef __bf16 bf2v __attribute__((ext_vector_type(2)));
    union { bf2v v; unsigned int u; } cv;
    cv.v[0] = (__bf16)k0;
    cv.v[1] = (__bf16)k1;
    return cv.u;
}

// Tables with the SCALED d2 fold: MFMA emits z = c3sq*d2 directly.
//   quads 0..2 of B hold w = -2*c3sq*y (split hi,hi,lo AFTER fp32 scaling)
//   quad 3: A {1,1,csx_hi,csx_lo} x B {csy_hi,csy_lo,1,1}, c* = c3sq-scaled
// btbl K-order: slot k=8q+i -> j = 4q + (i&3) + (i>=4 ? 16 : 0), matching
// the REGISTER layout of the swapped first MFMA's C/D (lane holds m=n,
// j = quad*4+s per tile) so the transformed values ARE the A-fragment.
__global__ __launch_bounds__(256) void prep_frags(const float* __restrict__ ls,
                                                  const float* __restrict__ y,
                                                  const float* __restrict__ b,
                                                  bf8* __restrict__ ytbl,
                                                  bf8* __restrict__ btbl,
                                                  float4* __restrict__ outz) {
    const int tile = blockIdx.x * 4 + (threadIdx.x >> 6);  // 0..1023 (j16 tiles)
    const int lane = threadIdx.x & 63;
    const int n = lane & 15, quad = lane >> 4;

    // zero d_out: 256 blocks * 256 threads * 16B = 1 MB
    outz[blockIdx.x * 256 + threadIdx.x] = make_float4(0.f, 0.f, 0.f, 0.f);

    float lsv[DD];
#pragma unroll
    for (int d = 0; d < DD; ++d) lsv[d] = ls[d];

    const float4* yr4 = (const float4*)(y + (size_t)(tile * 16 + n) * DD);
    float4 ya = yr4[0], yb = yr4[1];
    float yv[DD] = {ya.x, ya.y, ya.z, ya.w, yb.x, yb.y, yb.z, yb.w};

    float syv = 0.f;
    unsigned short wh[DD], wl[DD];
#pragma unroll
    for (int d = 0; d < DD; ++d) {
        syv = fmaf(lsv[d] * yv[d], yv[d], syv);
        float w = -2.f * C3SQ * yv[d];          // scale in fp32, THEN split
        wh[d] = f2bf(w);
        wl[d] = f2bf(w - bf2f(wh[d]));
    }

    bf8 fr;
    if (quad < 3) {
#pragma unroll
        for (int d = 0; d < DD; ++d)
            fr[d] = (short)((quad == 2) ? wl[d] : wh[d]);
    } else {
        float csy = C3SQ * syv;
        unsigned short sh = f2bf(csy);
        unsigned short sl = f2bf(csy - bf2f(sh));
        fr[0] = (short)sh;      // k=24: 1 * csy_hi
        fr[1] = (short)sl;      // k=25: 1 * csy_lo
        fr[2] = BF16_ONE;       // k=26: csx_hi * 1
        fr[3] = BF16_ONE;       // k=27: csx_lo * 1
        fr[4] = 0; fr[5] = 0; fr[6] = 0; fr[7] = 0;
    }
    ytbl[tile * 64 + lane] = fr;

    if (tile < MM / 32) {             // j32 tiles for phase B, register K-order
        bf8 bfr;
#pragma unroll
        for (int s = 0; s < 8; ++s) {
            int k = quad * 8 + s;
            int q = k >> 3, r = k & 7;
            int jl = q * 4 + (r & 3) + ((r & 4) ? 16 : 0);
            float bv = b[(size_t)(tile * 32 + jl) * DV + n];
            bfr[s] = (short)f2bf(bv);
        }
        btbl[tile * 64 + lane] = bfr;
    }
}

// R17 = R16 (zero-LDS operand-swap structure, proven 84.4us) + two issue
// trims from the 607cy/iter VALU budget (77% busy, trans ~= 65% of issue):
//  - pk2 via native __bf16 casts -> fused v_cvt_pk_bf16_f32 (was the 3-instr
//    fallback: the __has_builtin guard never fired on gfx950, m240).
//    -16 instr/iter.
//  - 1-deep table prefetch under #pragma unroll 2 (rotation movs renamed
//    away by the unroll; R13's version paid movs + a scalarization tax).
//    Targets the 23% non-issue gap = vmcnt stalls on the 3 L2 loads/iter.
//    Wrap-around index keeps the dead last prefetch in-chunk (no OOB).
__global__ __launch_bounds__(256, 8) void matern_mfma(const float* __restrict__ ls,
                                                      const float* __restrict__ x,
                                                      const bf8* __restrict__ ytbl,
                                                      const bf8* __restrict__ btbl,
                                                      float* __restrict__ out) {
    const int t = threadIdx.x;
    const int lane = t & 63, wave = t >> 6;
    const int n = lane & 15, quad = lane >> 4;
    const int waverow = blockIdx.x * ROWS_BLK + wave * ROWS_WAVE;

    float lsv[DD];
#pragma unroll
    for (int d = 0; d < DD; ++d) lsv[d] = ls[d];

    // A-frags (used as B operand now; same lane layout: lane&15 = x-row):
    // quad 0/2 -> xls_hi, quad 1 -> xls_lo, quad 3 -> {1,1,csx_hi,csx_lo}
    bf8 afrag[MT];
#pragma unroll
    for (int mt = 0; mt < MT; ++mt) {
        const float* xr = x + (size_t)(waverow + mt * 16 + n) * DD;
        float sx = 0.f;
        unsigned short xh[DD], xl[DD];
#pragma unroll
        for (int d = 0; d < DD; ++d) {
            float xv = xr[d];
            float xlsv = lsv[d] * xv;
            sx = fmaf(xlsv, xv, sx);
            xh[d] = f2bf(xlsv);
            xl[d] = f2bf(xlsv - bf2f(xh[d]));
        }
        bf8 fr;
        if (quad == 3) {
            float csx = C3SQ * sx;               // scale in fp32, THEN split
            unsigned short sh = f2bf(csx);
            unsigned short sl = f2bf(csx - bf2f(sh));
            fr[0] = BF16_ONE;   // k=24: 1 * csy_hi
            fr[1] = BF16_ONE;   // k=25: 1 * csy_lo
            fr[2] = (short)sh;  // k=26: csx_hi * 1
            fr[3] = (short)sl;  // k=27: csx_lo * 1
            fr[4] = 0; fr[5] = 0; fr[6] = 0; fr[7] = 0;
        } else {
#pragma unroll
            for (int d = 0; d < DD; ++d)
                fr[d] = (short)((quad == 1) ? xl[d] : xh[d]);
        }
        afrag[mt] = fr;
    }

    f32x4 acc[MT];
#pragma unroll
    for (int mt = 0; mt < MT; ++mt) acc[mt] = (f32x4){0.f, 0.f, 0.f, 0.f};

    const int tile16base = blockIdx.y * (JCHUNK / 16);
    const int tile32base = blockIdx.y * (JCHUNK / 32);

    const f32x4 z4 = (f32x4){0.f, 0.f, 0.f, 0.f};   // loop-invariant C=0

    // prologue loads for it=0
    bf8 yA = ytbl[(size_t)(tile16base) * 64 + lane];
    bf8 yB = ytbl[(size_t)(tile16base + 1) * 64 + lane];
    bf8 bb = btbl[(size_t)(tile32base) * 64 + lane];

#pragma unroll 2
    for (int it = 0; it < J32; ++it) {
        // prefetch it+1 (wrap keeps the dead last prefetch in-chunk/in-bounds)
        const int nx = (it + 1) & (J32 - 1);
        bf8 nyA = ytbl[(size_t)(tile16base + nx * 2) * 64 + lane];
        bf8 nyB = ytbl[(size_t)(tile16base + nx * 2 + 1) * 64 + lane];
        bf8 nbb = btbl[(size_t)(tile32base + nx) * 64 + lane];

#pragma unroll
        for (int mt = 0; mt < MT; ++mt) {
            // SWAPPED operands: D = z^T, lane (n,quad) holds
            // z[j = quad*4+s][m = n] for each 16-wide j-tile.
            f32x4 s0 = __builtin_amdgcn_mfma_f32_16x16x32_bf16(yA, afrag[mt], z4, 0, 0, 0);
            f32x4 s1 = __builtin_amdgcn_mfma_f32_16x16x32_bf16(yB, afrag[mt], z4, 0, 0, 0);
            // Transform in registers; pack as the next MFMA's A-fragment:
            // slot k=8*quad+i -> j = 4*quad+(i&3) + (i>=4)*16  (btbl matches)
            union { bf8 v; unsigned int u[4]; } pa;
            pa.u[0] = pk2(ktrans(s0[0]), ktrans(s0[1]));
            pa.u[1] = pk2(ktrans(s0[2]), ktrans(s0[3]));
            pa.u[2] = pk2(ktrans(s1[0]), ktrans(s1[1]));
            pa.u[3] = pk2(ktrans(s1[2]), ktrans(s1[3]));
            acc[mt] = __builtin_amdgcn_mfma_f32_16x16x32_bf16(pa.v, bb, acc[mt], 0, 0, 0);
        }
        yA = nyA; yB = nyB; bb = nbb;
    }

    // Epilogue: D layout row=quad*4+s (=m), col=n (=v); JSPLIT partials via atomics
#pragma unroll
    for (int mt = 0; mt < MT; ++mt)
#pragma unroll
        for (int s = 0; s < 4; ++s) {
            const int row = waverow + mt * 16 + quad * 4 + s;
            atomicAdd(out + (size_t)row * DV + n, acc[mt][s]);
        }
}

extern "C" void kernel_launch(void* const* d_in, const int* in_sizes, int n_in,
                              void* d_out, int out_size, void* d_ws, size_t ws_size,
                              hipStream_t stream) {
    const float* ls = (const float*)d_in[0];
    const float* x  = (const float*)d_in[1];
    const float* y  = (const float*)d_in[2];
    const float* b  = (const float*)d_in[3];
    float* out = (float*)d_out;

    char* ws = (char*)d_ws;
    bf8* ytbl = (bf8*)ws;                        // 1024*64*16B = 1 MB
    bf8* btbl = (bf8*)(ws + (1 << 20));          // 512*64*16B  = 512 KB

    prep_frags<<<MM / 64, 256, 0, stream>>>(ls, y, b, ytbl, btbl, (float4*)out);
    matern_mfma<<<dim3(NN / ROWS_BLK, JSPLIT), 256, 0, stream>>>(ls, x, ytbl, btbl, out);
}